// Round 1
// baseline (45.441 us; speedup 1.0000x reference)
//
#include <hip/hip_runtime.h>

// OuterProductMean on MI355X.
// out[i,j,p] = b2[p] + sum_{c,d} W2[p, c*32+d] * x[i,d] * x[j,c]
//   with x = seq @ W1^T + b1, L=512, IN=256, DM=32, PD=64.
// Factored: Y[i,p,c] = sum_d W2[p,c*32+d]*x[i,d]  (4 MB scratch)
//           out[i,j,p] = b2[p] + sum_c x[j,c]*Y[i,p,c]
// FLOPs drop 34.4 GF -> 1.14 GF; kernel 3 is bound by the 67 MB output write.

static constexpr int LL  = 512;
static constexpr int IND = 256;
static constexpr int DM  = 32;   // DIM_MSA
static constexpr int PD  = 64;   // PAIR_DIM

// ---------------- phase 1: x = seq @ W1^T + b1 -> xg [512][32], xTg [32][512]
__global__ __launch_bounds__(256) void k_proj1(const float* __restrict__ seq,
                                               const float* __restrict__ W1,
                                               const float* __restrict__ b1,
                                               float* __restrict__ xg,
                                               float* __restrict__ xTg) {
  __shared__ float part[8][DM];
  const int i   = blockIdx.x;
  const int t   = threadIdx.x;
  const int d   = t & 31;   // output channel
  const int seg = t >> 5;   // 8-way split of the K=256 dot
  const float* srow = seq + (size_t)i * IND + seg * 32;
  const float* wrow = W1  + (size_t)d * IND + seg * 32;
  float acc = 0.f;
#pragma unroll
  for (int k = 0; k < 32; k += 4) {
    const float4 s4 = *(const float4*)(srow + k);
    const float4 w4 = *(const float4*)(wrow + k);
    acc = fmaf(s4.x, w4.x, acc);
    acc = fmaf(s4.y, w4.y, acc);
    acc = fmaf(s4.z, w4.z, acc);
    acc = fmaf(s4.w, w4.w, acc);
  }
  part[seg][d] = acc;
  __syncthreads();
  if (t < DM) {
    float s = b1[t];
#pragma unroll
    for (int g = 0; g < 8; ++g) s += part[g][t];
    xg[i * DM + t]  = s;
    xTg[t * LL + i] = s;
  }
}

// ---------------- phase 2: Y[i][c][p] = sum_d W2[p][c*32+d] * x[i][d]
// One block handles 4 consecutive i. Yg layout [i][c][p] so phase 3 stages
// it with a straight linear copy.
__global__ __launch_bounds__(256) void k_proj2pre(const float* __restrict__ xg,
                                                  const float* __restrict__ W2,
                                                  float* __restrict__ Yg) {
  __shared__ float xs[4][DM];
  const int i0 = blockIdx.x * 4;
  const int t  = threadIdx.x;
  if (t < 128) xs[t >> 5][t & 31] = xg[i0 * DM + t];
  __syncthreads();
  const int p  = t & 63;
  const int c8 = t >> 6;  // 0..3
#pragma unroll
  for (int cc = 0; cc < 8; ++cc) {
    const int c = c8 * 8 + cc;
    const float* w = W2 + (size_t)p * (DM * DM) + c * DM;  // 32 contiguous floats
    float wv[DM];
#pragma unroll
    for (int q = 0; q < 8; ++q) {
      const float4 v = *(const float4*)(w + q * 4);
      wv[q * 4 + 0] = v.x; wv[q * 4 + 1] = v.y;
      wv[q * 4 + 2] = v.z; wv[q * 4 + 3] = v.w;
    }
#pragma unroll
    for (int ii = 0; ii < 4; ++ii) {
      float a = 0.f;
#pragma unroll
      for (int d = 0; d < 32; ++d) a = fmaf(wv[d], xs[ii][d], a);
      Yg[(size_t)(i0 + ii) * (DM * PD) + c * PD + p] = a;  // coalesced in p
    }
  }
}

// ---------------- phase 3: out[i,j,p] = b2[p] + sum_c xT[c][j] * Ys[c][p]
// Block = (i, half of j). LDS 40KB -> 4 blocks/CU. Thread tile 8j x 8p.
__global__ __launch_bounds__(256) void k_outer(const float* __restrict__ xTg,
                                               const float* __restrict__ Yg,
                                               const float* __restrict__ b2,
                                               float* __restrict__ out) {
  __shared__ __align__(16) float xT[DM][256];  // [c][j_local] 32 KB
  __shared__ __align__(16) float Ys[DM][PD];   // [c][p]        8 KB
  const int bid   = blockIdx.x;
  const int i     = bid >> 1;
  const int jbase = (bid & 1) << 8;  // 0 or 256
  const int t     = threadIdx.x;

  // stage Y_i : 2048 floats = 512 float4, linear copy
  {
    const float4* src = (const float4*)(Yg + (size_t)i * (DM * PD));
    float4* dst = (float4*)&Ys[0][0];
    dst[t]       = src[t];
    dst[t + 256] = src[t + 256];
  }
  // stage xT slice: 32 rows x 256 floats = 2048 float4
  {
    const float4* src = (const float4*)xTg;   // row stride 128 float4
    float4* dst = (float4*)&xT[0][0];
#pragma unroll
    for (int k = 0; k < 8; ++k) {
      const int q   = t + k * 256;
      const int c   = q >> 6;
      const int jl4 = q & 63;
      dst[q] = src[c * 128 + (jbase >> 2) + jl4];
    }
  }
  __syncthreads();

  const int pt = t & 7;
  const int jt = t >> 3;       // 0..31
  const int p0 = pt * 8;
  const int j0 = jt * 8;

  const float4 bA = *(const float4*)(b2 + p0);
  const float4 bB = *(const float4*)(b2 + p0 + 4);

  float acc[8][8];
#pragma unroll
  for (int jj = 0; jj < 8; ++jj) {
    acc[jj][0] = bA.x; acc[jj][1] = bA.y; acc[jj][2] = bA.z; acc[jj][3] = bA.w;
    acc[jj][4] = bB.x; acc[jj][5] = bB.y; acc[jj][6] = bB.z; acc[jj][7] = bB.w;
  }

#pragma unroll 4
  for (int c = 0; c < DM; ++c) {
    const float4 xa = *(const float4*)&xT[c][j0];
    const float4 xb = *(const float4*)&xT[c][j0 + 4];
    const float4 ya = *(const float4*)&Ys[c][p0];
    const float4 yb = *(const float4*)&Ys[c][p0 + 4];
    const float xv[8] = {xa.x, xa.y, xa.z, xa.w, xb.x, xb.y, xb.z, xb.w};
    const float yv[8] = {ya.x, ya.y, ya.z, ya.w, yb.x, yb.y, yb.z, yb.w};
#pragma unroll
    for (int jj = 0; jj < 8; ++jj)
#pragma unroll
      for (int pp = 0; pp < 8; ++pp)
        acc[jj][pp] = fmaf(xv[jj], yv[pp], acc[jj][pp]);
  }

  const int jglob0 = jbase + j0;
#pragma unroll
  for (int jj = 0; jj < 8; ++jj) {
    float* orow = out + ((size_t)i * LL + jglob0 + jj) * PD + p0;
    const float4 oA = {acc[jj][0], acc[jj][1], acc[jj][2], acc[jj][3]};
    const float4 oB = {acc[jj][4], acc[jj][5], acc[jj][6], acc[jj][7]};
    *(float4*)(orow)     = oA;
    *(float4*)(orow + 4) = oB;
  }
}

extern "C" void kernel_launch(void* const* d_in, const int* in_sizes, int n_in,
                              void* d_out, int out_size, void* d_ws, size_t ws_size,
                              hipStream_t stream) {
  const float* seq = (const float*)d_in[0];
  const float* W1  = (const float*)d_in[1];
  const float* b1  = (const float*)d_in[2];
  const float* W2  = (const float*)d_in[3];
  const float* b2  = (const float*)d_in[4];
  float* out = (float*)d_out;

  // ws layout (floats): xg[512*32] | xTg[32*512] | Yg[512*32*64]  => ~4.33 MB
  float* xg  = (float*)d_ws;
  float* xTg = xg + LL * DM;
  float* Yg  = xTg + DM * LL;

  k_proj1<<<LL, 256, 0, stream>>>(seq, W1, b1, xg, xTg);
  k_proj2pre<<<LL / 4, 256, 0, stream>>>(xg, W2, Yg);
  k_outer<<<LL * 2, 256, 0, stream>>>(xTg, Yg, b2, out);
}